// Round 8
// baseline (151.398 us; speedup 1.0000x reference)
//
#include <hip/hip_runtime.h>
#include <math.h>

#define B 2
#define T 512
#define C 512
#define H 64

// scale = C^-0.5 = 1/sqrt(512)
#define SCALE 0.044194173824159216f

static __device__ __forceinline__ float qnan() { return __builtin_nanf(""); }

// ---------------------------------------------------------------------------
// Kernel 1 (fused): scan + qkv + relsum. Grid = 256 blocks x 256 threads.
// Block handles 4 consecutive (b,t) rows: b = bid>>7, j0 = (bid&127)*4.
// Phase 0: stage tok (batch) + x (4 rows) to LDS, zero tables.
// Phase 1: wave 0 = full scan for batch b (regs+shuffles; results to LDS);
//          waves 1..3 = matrix m=wave-1 projection for the 4 rows
//          (R7 pattern: full-W float4 stream, 4 row-accums, shfl_xor fold).
// Phase 2: wave w = relsum for row j0+w (129 pitch bins + L time runs +
//          pos window; per-lane h component, no reduce), write k', v'.
// No global scan outputs; q written in phase 1.
// ---------------------------------------------------------------------------
__global__ __launch_bounds__(256) void fused_kernel(
    const int* __restrict__ tok, const float* __restrict__ x,
    const float* __restrict__ Wq, const float* __restrict__ Wk,
    const float* __restrict__ Wv,
    const float* __restrict__ Ek_pos, const float* __restrict__ Ev_pos,
    const float* __restrict__ Ek_time, const float* __restrict__ Ev_time,
    const float* __restrict__ Ek_pitch, const float* __restrict__ Ev_pitch,
    float* __restrict__ q, float* __restrict__ k, float* __restrict__ v) {
    int bid = blockIdx.x;
    int b = bid >> 7;
    int j0 = (bid & 127) * 4;
    int tid = threadIdx.x;
    int wave = tid >> 6;
    int lane = tid & 63;

    __shared__ int   tks[T];
    __shared__ float ptv[T];      // prop_t for batch b
    __shared__ float ppv[T];      // shifted prop_p for batch b
    __shared__ float tvalL[520];  // time run values
    __shared__ int   cnts[520];   // time run lengths
    __shared__ int   hist[129];   // pitch histogram
    __shared__ int   metaL[2];    // L, nanT
    __shared__ int   nanPc;
    __shared__ float xs[4 * C];   // 4 x-rows
    __shared__ float kvK[4][64];
    __shared__ float kvV[4][64];

    // ---- Phase 0: stage + zero ----
    {
        const int* tb = tok + b * T;
        tks[tid] = tb[tid];
        tks[tid + 256] = tb[tid + 256];
        const float4* xv4 = (const float4*)(x + (size_t)(b * T + j0) * C);
        float4* xs4 = (float4*)xs;
        xs4[tid] = xv4[tid];
        xs4[tid + 256] = xv4[tid + 256];
        for (int i = tid; i < 520; i += 256) cnts[i] = 0;
        if (tid < 129) hist[tid] = 0;
        if (tid == 255) nanPc = 0;
    }
    __syncthreads();

    if (wave == 0) {
        // ================= scan (wave 0 only, reg/shuffle based) ===========
        const int p0 = lane * 8;
        unsigned long long lowmask = lane ? ((1ull << lane) - 1ull) : 0ull;

        // ---- time scan ----
        float tv[8];
        {
            float lsum[8];
            bool lflag[8];
            float s = 0.f;
            bool f = false;
#pragma unroll
            for (int u = 0; u < 8; ++u) {
                int tk = tks[p0 + u];
                if (tk >= 288) { s += (float)(tk - 288); f = true; }
                lsum[u] = s;
                lflag[u] = f;
            }
            float inc = s;
#pragma unroll
            for (int off = 1; off < 64; off <<= 1) {
                float o = __shfl_up(inc, off);
                if (lane >= off) inc += o;
            }
            float ex = inc - s;
            unsigned long long fmask = __ballot(f);
            bool exf = (fmask & lowmask) != 0ull;
#pragma unroll
            for (int u = 0; u < 8; ++u) {
                bool have = exf | lflag[u];
                tv[u] = have ? rintf((ex + lsum[u] + 1.0f) / 10.0f) : qnan();
                ptv[p0 + u] = tv[u];
            }
        }

        // ---- pitch scan (copy-last-valid) ----
        float fv[8];
        {
            bool lvalid[8];
            float cv = 0.f;
            bool cvd = false;
#pragma unroll
            for (int u = 0; u < 8; ++u) {
                int tk = tks[p0 + u];
                if (tk < 256) {
                    cv = (float)((tk >= 128 ? tk - 128 : tk) + 1);
                    cvd = true;
                }
                fv[u] = cv;
                lvalid[u] = cvd;
            }
            unsigned long long vmask = __ballot(cvd);
            unsigned long long lower = vmask & lowmask;
            bool exvd = lower != 0ull;
            int src = 63 - __clzll(lower | 1ull);
            float exv = __shfl(cv, src);
#pragma unroll
            for (int u = 0; u < 8; ++u) {
                bool hv = exvd | lvalid[u];
                fv[u] = lvalid[u] ? fv[u] : exv;
                fv[u] = hv ? fv[u] : qnan();
            }
        }

        // ---- shifted pitch -> ppv + histogram ----
        {
            float nf0 = __shfl_down(fv[0], 1);  // next lane's fv[0]
#pragma unroll
            for (int u = 0; u < 8; ++u) {
                float sv = (u < 7) ? fv[u + 1] : ((lane == 63) ? fv[7] : nf0);
                ppv[p0 + u] = sv;
                if (sv == sv) atomicAdd(&hist[(int)sv - 1], 1);
                else atomicAdd(&nanPc, 1);
            }
        }

        // ---- time RLE (regs + shuffles) ----
        {
            float pl7 = __shfl_up(tv[7], 1);  // prev lane's tv[7]
            int lstart[8];
            int lcnt = 0, lnan = 0;
#pragma unroll
            for (int u = 0; u < 8; ++u) {
                float cur = tv[u];
                bool val = (cur == cur);
                float pv = (u > 0) ? tv[u - 1] : pl7;
                bool st = false;
                if (val) {
                    if (p0 + u == 0) st = true;
                    else st = !(pv == pv) || (pv != cur);
                } else lnan++;
                lstart[u] = st;
                lcnt += st;
            }
            int incs = lcnt;
#pragma unroll
            for (int off = 1; off < 64; off <<= 1) {
                int o = __shfl_up(incs, off);
                if (lane >= off) incs += o;
            }
            int base = incs - lcnt;
            int Lruns = __shfl(incs, 63);
            int tn = lnan;
#pragma unroll
            for (int off = 32; off; off >>= 1) tn += __shfl_down(tn, off);
            tn = __shfl(tn, 0);

            int s2 = base;
#pragma unroll
            for (int u = 0; u < 8; ++u) {
                float cur = tv[u];
                if (lstart[u]) { tvalL[s2] = cur; s2++; }
                if (cur == cur) atomicAdd(&cnts[s2 - 1], 1);
            }
            if (lane == 0) { metaL[0] = Lruns; metaL[1] = tn; }
        }
    } else {
        // ================= qkv: wave handles matrix m = wave-1 =============
        int m = wave - 1;
        const float* Wm = (m == 0) ? Wq : ((m == 1) ? Wk : Wv);
        int g = lane >> 4;
        int c4 = lane & 15;
        const float4* W4 = (const float4*)Wm;

        float4 a0 = make_float4(0.f, 0.f, 0.f, 0.f);
        float4 a1 = a0, a2 = a0, a3 = a0;
#pragma unroll 4
        for (int u = 0; u < 128; ++u) {
            int kk = u * 4 + g;
            float4 w4 = W4[kk * 16 + c4];
            float x0 = xs[kk];
            float x1 = xs[C + kk];
            float x2 = xs[2 * C + kk];
            float x3 = xs[3 * C + kk];
            a0.x = fmaf(x0, w4.x, a0.x); a0.y = fmaf(x0, w4.y, a0.y);
            a0.z = fmaf(x0, w4.z, a0.z); a0.w = fmaf(x0, w4.w, a0.w);
            a1.x = fmaf(x1, w4.x, a1.x); a1.y = fmaf(x1, w4.y, a1.y);
            a1.z = fmaf(x1, w4.z, a1.z); a1.w = fmaf(x1, w4.w, a1.w);
            a2.x = fmaf(x2, w4.x, a2.x); a2.y = fmaf(x2, w4.y, a2.y);
            a2.z = fmaf(x2, w4.z, a2.z); a2.w = fmaf(x2, w4.w, a2.w);
            a3.x = fmaf(x3, w4.x, a3.x); a3.y = fmaf(x3, w4.y, a3.y);
            a3.z = fmaf(x3, w4.z, a3.z); a3.w = fmaf(x3, w4.w, a3.w);
        }
#pragma unroll
        for (int mask = 16; mask <= 32; mask <<= 1) {
            a0.x += __shfl_xor(a0.x, mask); a0.y += __shfl_xor(a0.y, mask);
            a0.z += __shfl_xor(a0.z, mask); a0.w += __shfl_xor(a0.w, mask);
            a1.x += __shfl_xor(a1.x, mask); a1.y += __shfl_xor(a1.y, mask);
            a1.z += __shfl_xor(a1.z, mask); a1.w += __shfl_xor(a1.w, mask);
            a2.x += __shfl_xor(a2.x, mask); a2.y += __shfl_xor(a2.y, mask);
            a2.z += __shfl_xor(a2.z, mask); a2.w += __shfl_xor(a2.w, mask);
            a3.x += __shfl_xor(a3.x, mask); a3.y += __shfl_xor(a3.y, mask);
            a3.z += __shfl_xor(a3.z, mask); a3.w += __shfl_xor(a3.w, mask);
        }
        if (g == 0) {
            if (m == 0) {
                size_t r0 = (size_t)(b * T + j0);
                ((float4*)(q + (r0 + 0) * H))[c4] = a0;
                ((float4*)(q + (r0 + 1) * H))[c4] = a1;
                ((float4*)(q + (r0 + 2) * H))[c4] = a2;
                ((float4*)(q + (r0 + 3) * H))[c4] = a3;
            } else if (m == 1) {
                ((float4*)&kvK[0][0])[c4] = a0;
                ((float4*)&kvK[1][0])[c4] = a1;
                ((float4*)&kvK[2][0])[c4] = a2;
                ((float4*)&kvK[3][0])[c4] = a3;
            } else {
                ((float4*)&kvV[0][0])[c4] = a0;
                ((float4*)&kvV[1][0])[c4] = a1;
                ((float4*)&kvV[2][0])[c4] = a2;
                ((float4*)&kvV[3][0])[c4] = a3;
            }
        }
    }
    __syncthreads();

    // ================= relsum: wave w -> row j = j0+w ======================
    int j = j0 + wave;
    int L = metaL[0];
    int nanT = metaL[1];
    int nanP = nanPc;
    float pjt = ptv[j];
    float pjp = ppv[j];
    bool pvalid = (pjp == pjp);
    int ipjp = pvalid ? (int)pjp : 0;

    float aK = 0.f, aV = 0.f;

    // ---- pitch: 129 bins; idx = ipjp+127-e exact; NaN -> 0 ----
#pragma unroll 4
    for (int e = 0; e < 129; ++e) {
        int cnt = hist[e];
        if (cnt) {
            int idx = pvalid ? (ipjp + 127 - e) : 0;
            float fc = (float)cnt;
            aK = fmaf(fc, Ek_pitch[idx * H + lane], aK);
            aV = fmaf(fc, Ev_pitch[idx * H + lane], aV);
        }
    }
    if (nanP) {
        float fc = (float)nanP;
        aK = fmaf(fc, Ek_pitch[lane], aK);
        aV = fmaf(fc, Ev_pitch[lane], aV);
    }

    // ---- time runs ----
#pragma unroll 2
    for (int r = 0; r < L; ++r) {
        int cnt = cnts[r];
        float dt = pjt - tvalL[r];
        int idx = (dt != dt) ? 0 : (int)fminf(fmaxf(dt, -200.f), 200.f) + 200;
        float fc = (float)cnt;
        aK = fmaf(fc, Ek_time[idx * H + lane], aK);
        aV = fmaf(fc, Ev_time[idx * H + lane], aV);
    }
    if (nanT) {
        float fc = (float)nanT;
        aK = fmaf(fc, Ek_time[lane], aK);
        aV = fmaf(fc, Ev_time[lane], aV);
    }

    // ---- pos window + edge multiplicities ----
    int lo = max(-25, j - (T - 1));
    int hi = min(25, j);
#pragma unroll 4
    for (int d = lo; d <= hi; ++d) {
        aK += Ek_pos[(d + 25) * H + lane];
        aV += Ev_pos[(d + 25) * H + lane];
    }
    {
        float c50 = (float)max(j - 25, 0);
        float c0 = (float)max((T - 26) - j, 0);
        aK = fmaf(c50, Ek_pos[50 * H + lane], aK);
        aK = fmaf(c0, Ek_pos[0 * H + lane], aK);
        aV = fmaf(c50, Ev_pos[50 * H + lane], aV);
        aV = fmaf(c0, Ev_pos[0 * H + lane], aV);
    }

    size_t o = (size_t)(b * T + j) * H + lane;
    k[o] = SCALE * kvK[wave][lane] + aK;
    v[o] = kvV[wave][lane] + aV;
}

// ---------------------------------------------------------------------------
// Kernel 2: flash-style causal attention (unchanged from R7).
// ---------------------------------------------------------------------------
__global__ __launch_bounds__(256) void attn_kernel(const float* __restrict__ q,
                                                   const float* __restrict__ kp,
                                                   const float* __restrict__ vp,
                                                   float* __restrict__ out) {
    int b = blockIdx.x >> 7;
    int g = blockIdx.x & 127;
    int tid = threadIdx.x;
    int wave = tid >> 6;
    int lane = tid & 63;

    int t = (wave < 2) ? (2 * g + wave) : (511 - 2 * g - (wave - 2));
    int ns = t + 1;

    __shared__ float kt[64 * 65];
    __shared__ float vt[64 * 64];
    __shared__ float qs[4][64];
    __shared__ float pS[4][64];

    qs[wave][lane] = q[((size_t)b * T + t) * H + lane];

    const float* kb = kp + (size_t)b * T * H;
    const float* vb = vp + (size_t)b * T * H;
    int ntiles = (512 - 2 * g + 63) / 64;

    float m = -INFINITY;
    float l = 0.f;
    float acc = 0.f;

    for (int it = 0; it < ntiles; ++it) {
        int s0 = it * 64;

#pragma unroll
        for (int i = 0; i < 4; ++i) {
            int f = i * 256 + tid;
            int r = f >> 4;
            int c0 = (f & 15) << 2;
            int sr = min(s0 + r, T - 1);
            const float4 kv = *(const float4*)(kb + (size_t)sr * H + c0);
            const float4 vv = *(const float4*)(vb + (size_t)sr * H + c0);
            kt[r * 65 + c0 + 0] = kv.x;
            kt[r * 65 + c0 + 1] = kv.y;
            kt[r * 65 + c0 + 2] = kv.z;
            kt[r * 65 + c0 + 3] = kv.w;
            *(float4*)(vt + r * 64 + c0) = vv;
        }
        __syncthreads();

        if (s0 < ns) {
            int s = s0 + lane;
            float sc = -INFINITY;
            if (s < ns) {
                const float* kr = kt + lane * 65;
                const float* qw = qs[wave];
                float d0 = 0.f, d1 = 0.f, d2 = 0.f, d3 = 0.f;
#pragma unroll
                for (int c = 0; c < 64; c += 4) {
                    d0 = fmaf(qw[c + 0], kr[c + 0], d0);
                    d1 = fmaf(qw[c + 1], kr[c + 1], d1);
                    d2 = fmaf(qw[c + 2], kr[c + 2], d2);
                    d3 = fmaf(qw[c + 3], kr[c + 3], d3);
                }
                sc = (d0 + d1) + (d2 + d3);
            }
            float mt = sc;
#pragma unroll
            for (int off = 32; off; off >>= 1) mt = fmaxf(mt, __shfl_xor(mt, off));
            float mnew = fmaxf(m, mt);
            float alpha = __expf(m - mnew);
            float p = (s < ns) ? __expf(sc - mnew) : 0.f;
            l = l * alpha + p;
            pS[wave][lane] = p;
            m = mnew;

            float a0 = 0.f, a1 = 0.f, a2 = 0.f, a3 = 0.f;
            int smax = min(64, ns - s0);
            const float* pw = pS[wave];
            int ss = 0;
            for (; ss + 4 <= smax; ss += 4) {
                a0 = fmaf(pw[ss + 0], vt[(ss + 0) * 64 + lane], a0);
                a1 = fmaf(pw[ss + 1], vt[(ss + 1) * 64 + lane], a1);
                a2 = fmaf(pw[ss + 2], vt[(ss + 2) * 64 + lane], a2);
                a3 = fmaf(pw[ss + 3], vt[(ss + 3) * 64 + lane], a3);
            }
            for (; ss < smax; ++ss)
                a0 = fmaf(pw[ss], vt[ss * 64 + lane], a0);
            acc = acc * alpha + ((a0 + a1) + (a2 + a3));
        }
        __syncthreads();
    }

    float lt = l;
#pragma unroll
    for (int off = 32; off; off >>= 1) lt += __shfl_xor(lt, off);

    out[((size_t)b * T + t) * H + lane] = acc / lt;
}

// ---------------------------------------------------------------------------
extern "C" void kernel_launch(void* const* d_in, const int* in_sizes, int n_in,
                              void* d_out, int out_size, void* d_ws, size_t ws_size,
                              hipStream_t stream) {
    const float* x        = (const float*)d_in[0];
    const int*   tok      = (const int*)d_in[1];
    const float* Wk       = (const float*)d_in[2];
    const float* Wq       = (const float*)d_in[3];
    const float* Wv       = (const float*)d_in[4];
    const float* Ek_pos   = (const float*)d_in[5];
    const float* Ev_pos   = (const float*)d_in[6];
    const float* Ek_time  = (const float*)d_in[7];
    const float* Ev_time  = (const float*)d_in[8];
    const float* Ek_pitch = (const float*)d_in[9];
    const float* Ev_pitch = (const float*)d_in[10];
    float* out = (float*)d_out;

    float* ws = (float*)d_ws;
    float* q = ws;                 // B*T*H
    float* k = q + B * T * H;      // B*T*H (k')
    float* v = k + B * T * H;      // B*T*H (v')

    fused_kernel<<<B * 128, 256, 0, stream>>>(tok, x, Wq, Wk, Wv,
                                              Ek_pos, Ev_pos, Ek_time, Ev_time,
                                              Ek_pitch, Ev_pitch, q, k, v);
    attn_kernel<<<B * 128, 256, 0, stream>>>(q, k, v, out);
}

// Round 9
// 124.753 us; speedup vs baseline: 1.2136x; 1.2136x over previous
//
#include <hip/hip_runtime.h>
#include <math.h>

#define B 2
#define T 512
#define C 512
#define H 64

// scale = C^-0.5 = 1/sqrt(512)
#define SCALE 0.044194173824159216f

static __device__ __forceinline__ float qnan() { return __builtin_nanf(""); }

// ---------------------------------------------------------------------------
// Kernel 1: qkv projection (blocks 0..191, R7 structure) + token scans
// (blocks 192..193, one wave each). Scan parallelism unchanged from R7;
// saves one dispatch + stream gap.
// ---------------------------------------------------------------------------
__global__ __launch_bounds__(256) void qkv_scan_kernel(
    const float* __restrict__ x, const int* __restrict__ tok,
    const float* __restrict__ Wq, const float* __restrict__ Wk,
    const float* __restrict__ Wv,
    float* __restrict__ q, float* __restrict__ k, float* __restrict__ v,
    float* __restrict__ prop_t, float* __restrict__ prop_p,
    int* __restrict__ cntP, int* __restrict__ meta,
    float* __restrict__ tval, int* __restrict__ tcnt) {
    int bid = blockIdx.x;
    int tid = threadIdx.x;
    int wave = tid >> 6;
    int lane = tid & 63;

    __shared__ float xs[16 * C];   // qkv path (32 KB)
    __shared__ int   tks[T];       // scan path
    __shared__ int   cnts[520];
    __shared__ int   hist[129];
    __shared__ int   nanPc;

    if (bid < 192) {
        // ================= qkv: R7 pattern =================
        int rg = bid & 63;             // 16-row group
        int m = bid >> 6;              // 0=q, 1=k, 2=v
        int g = lane >> 4;
        int c4 = lane & 15;

        const float* Wm = (m == 0) ? Wq : ((m == 1) ? Wk : Wv);
        float* Om = (m == 0) ? q : ((m == 1) ? k : v);

        const float4* xv4 = (const float4*)(x + (size_t)rg * 16 * C);
        float4* xs4 = (float4*)xs;
#pragma unroll
        for (int i = 0; i < 8; ++i) xs4[tid + 256 * i] = xv4[tid + 256 * i];
        __syncthreads();

        const float4* W4 = (const float4*)Wm;
        const float* xr = xs + (wave * 4) * C;

        float4 a0 = make_float4(0.f, 0.f, 0.f, 0.f);
        float4 a1 = a0, a2 = a0, a3 = a0;
#pragma unroll 4
        for (int u = 0; u < 128; ++u) {
            int kk = u * 4 + g;
            float4 w4 = W4[kk * 16 + c4];
            float x0 = xr[kk];
            float x1 = xr[C + kk];
            float x2 = xr[2 * C + kk];
            float x3 = xr[3 * C + kk];
            a0.x = fmaf(x0, w4.x, a0.x); a0.y = fmaf(x0, w4.y, a0.y);
            a0.z = fmaf(x0, w4.z, a0.z); a0.w = fmaf(x0, w4.w, a0.w);
            a1.x = fmaf(x1, w4.x, a1.x); a1.y = fmaf(x1, w4.y, a1.y);
            a1.z = fmaf(x1, w4.z, a1.z); a1.w = fmaf(x1, w4.w, a1.w);
            a2.x = fmaf(x2, w4.x, a2.x); a2.y = fmaf(x2, w4.y, a2.y);
            a2.z = fmaf(x2, w4.z, a2.z); a2.w = fmaf(x2, w4.w, a2.w);
            a3.x = fmaf(x3, w4.x, a3.x); a3.y = fmaf(x3, w4.y, a3.y);
            a3.z = fmaf(x3, w4.z, a3.z); a3.w = fmaf(x3, w4.w, a3.w);
        }
#pragma unroll
        for (int mask = 16; mask <= 32; mask <<= 1) {
            a0.x += __shfl_xor(a0.x, mask); a0.y += __shfl_xor(a0.y, mask);
            a0.z += __shfl_xor(a0.z, mask); a0.w += __shfl_xor(a0.w, mask);
            a1.x += __shfl_xor(a1.x, mask); a1.y += __shfl_xor(a1.y, mask);
            a1.z += __shfl_xor(a1.z, mask); a1.w += __shfl_xor(a1.w, mask);
            a2.x += __shfl_xor(a2.x, mask); a2.y += __shfl_xor(a2.y, mask);
            a2.z += __shfl_xor(a2.z, mask); a2.w += __shfl_xor(a2.w, mask);
            a3.x += __shfl_xor(a3.x, mask); a3.y += __shfl_xor(a3.y, mask);
            a3.z += __shfl_xor(a3.z, mask); a3.w += __shfl_xor(a3.w, mask);
        }
        if (g == 0) {
            size_t row0 = (size_t)(rg * 16 + wave * 4);
            ((float4*)(Om + (row0 + 0) * H))[c4] = a0;
            ((float4*)(Om + (row0 + 1) * H))[c4] = a1;
            ((float4*)(Om + (row0 + 2) * H))[c4] = a2;
            ((float4*)(Om + (row0 + 3) * H))[c4] = a3;
        }
        return;
    }

    // ================= scan: blocks 192..193, wave 0 only =================
    int b = bid - 192;
    {
        const int* tb = tok + b * T;
        tks[tid] = tb[tid];
        tks[tid + 256] = tb[tid + 256];
        for (int i = tid; i < 520; i += 256) cnts[i] = 0;
        if (tid < 129) hist[tid] = 0;
        if (tid == 255) nanPc = 0;
    }
    __syncthreads();
    if (wave != 0) return;

    const int p0 = lane * 8;
    unsigned long long lowmask = lane ? ((1ull << lane) - 1ull) : 0ull;

    // ---- time scan ----
    float tv[8];
    {
        float lsum[8];
        bool lflag[8];
        float s = 0.f;
        bool f = false;
#pragma unroll
        for (int u = 0; u < 8; ++u) {
            int tk = tks[p0 + u];
            if (tk >= 288) { s += (float)(tk - 288); f = true; }
            lsum[u] = s;
            lflag[u] = f;
        }
        float inc = s;
#pragma unroll
        for (int off = 1; off < 64; off <<= 1) {
            float o = __shfl_up(inc, off);
            if (lane >= off) inc += o;
        }
        float ex = inc - s;
        unsigned long long fmask = __ballot(f);
        bool exf = (fmask & lowmask) != 0ull;
#pragma unroll
        for (int u = 0; u < 8; ++u) {
            bool have = exf | lflag[u];
            tv[u] = have ? rintf((ex + lsum[u] + 1.0f) / 10.0f) : qnan();
            prop_t[b * T + p0 + u] = tv[u];
        }
    }

    // ---- pitch scan (copy-last-valid) ----
    float fv[8];
    {
        bool lvalid[8];
        float cv = 0.f;
        bool cvd = false;
#pragma unroll
        for (int u = 0; u < 8; ++u) {
            int tk = tks[p0 + u];
            if (tk < 256) {
                cv = (float)((tk >= 128 ? tk - 128 : tk) + 1);
                cvd = true;
            }
            fv[u] = cv;
            lvalid[u] = cvd;
        }
        unsigned long long vmask = __ballot(cvd);
        unsigned long long lower = vmask & lowmask;
        bool exvd = lower != 0ull;
        int src = 63 - __clzll(lower | 1ull);
        float exv = __shfl(cv, src);
#pragma unroll
        for (int u = 0; u < 8; ++u) {
            bool hv = exvd | lvalid[u];
            fv[u] = lvalid[u] ? fv[u] : exv;
            fv[u] = hv ? fv[u] : qnan();
        }
    }

    // ---- shifted pitch + histogram ----
    {
        float nf0 = __shfl_down(fv[0], 1);  // next lane's fv[0]
#pragma unroll
        for (int u = 0; u < 8; ++u) {
            float sv = (u < 7) ? fv[u + 1] : ((lane == 63) ? fv[7] : nf0);
            prop_p[b * T + p0 + u] = sv;
            if (sv == sv) atomicAdd(&hist[(int)sv - 1], 1);
            else atomicAdd(&nanPc, 1);
        }
    }

    // ---- time RLE ----
    {
        float pl7 = __shfl_up(tv[7], 1);
        int lstart[8];
        int lcnt = 0, lnan = 0;
#pragma unroll
        for (int u = 0; u < 8; ++u) {
            float cur = tv[u];
            bool val = (cur == cur);
            float pv = (u > 0) ? tv[u - 1] : pl7;
            bool st = false;
            if (val) {
                if (p0 + u == 0) st = true;
                else st = !(pv == pv) || (pv != cur);
            } else lnan++;
            lstart[u] = st;
            lcnt += st;
        }
        int incs = lcnt;
#pragma unroll
        for (int off = 1; off < 64; off <<= 1) {
            int o = __shfl_up(incs, off);
            if (lane >= off) incs += o;
        }
        int base = incs - lcnt;
        int Lruns = __shfl(incs, 63);
        int tn = lnan;
#pragma unroll
        for (int off = 32; off; off >>= 1) tn += __shfl_down(tn, off);
        tn = __shfl(tn, 0);

        int s2 = base;
#pragma unroll
        for (int u = 0; u < 8; ++u) {
            float cur = tv[u];
            if (lstart[u]) { tval[b * 520 + s2] = cur; s2++; }
            if (cur == cur) atomicAdd(&cnts[s2 - 1], 1);
        }
        // same-wave DS ordering makes cnts/hist reads below safe
        for (int i = lane; i < Lruns; i += 64) tcnt[b * 520 + i] = cnts[i];
        for (int i = lane; i < 129; i += 64) cntP[b * 129 + i] = hist[i];
        if (lane == 0) {
            meta[b * 4] = Lruns;
            meta[b * 4 + 1] = tn;
        }
        if (lane == 1) meta[b * 4 + 2] = nanPc;
    }
}

// ---------------------------------------------------------------------------
// Kernel 2: relative-embedding sums (exact R7 version).
// ---------------------------------------------------------------------------
__global__ __launch_bounds__(256) void relsum_kernel(
    const float* __restrict__ prop_t, const float* __restrict__ prop_p,
    const int* __restrict__ cntP, const int* __restrict__ meta,
    const float* __restrict__ tval, const int* __restrict__ tcnt,
    const float* __restrict__ Ek_pos, const float* __restrict__ Ev_pos,
    const float* __restrict__ Ek_time, const float* __restrict__ Ev_time,
    const float* __restrict__ Ek_pitch, const float* __restrict__ Ev_pitch,
    float* __restrict__ k, float* __restrict__ v) {
    int b = blockIdx.x >> 9;
    int j = blockIdx.x & 511;
    int tid = threadIdx.x;
    int wave = tid >> 6;
    int c = tid & 63;

    __shared__ float tvL[520];
    __shared__ int tcL[520];
    __shared__ int cpL[132];
    __shared__ float redK[256];
    __shared__ float redV[256];

    int L = meta[b * 4];
    int nanT = meta[b * 4 + 1];
    int nanP = meta[b * 4 + 2];
    for (int i = tid; i < L; i += 256) {
        tvL[i] = tval[b * 520 + i];
        tcL[i] = tcnt[b * 520 + i];
    }
    if (tid < 129) cpL[tid] = cntP[b * 129 + tid];
    else if (tid < 132) cpL[tid] = 0;
    __syncthreads();

    float pjt = prop_t[b * T + j];
    float pjp = prop_p[b * T + j];
    bool pvalid = (pjp == pjp);
    int ipjp = pvalid ? (int)pjp : 0;

    float aK = 0.f, aV = 0.f;

#pragma unroll 3
    for (int i = 0; i < 33; ++i) {
        int e = wave + i * 4;
        int cnt = cpL[e];
        if (cnt) {
            int idx = pvalid ? (ipjp + 127 - e) : 0;
            float fc = (float)cnt;
            aK = fmaf(fc, Ek_pitch[idx * H + c], aK);
            aV = fmaf(fc, Ev_pitch[idx * H + c], aV);
        }
    }
    if (wave == 3 && nanP) {
        float fc = (float)nanP;
        aK = fmaf(fc, Ek_pitch[c], aK);
        aV = fmaf(fc, Ev_pitch[c], aV);
    }

#pragma unroll 2
    for (int r = wave; r < L; r += 4) {
        int cnt = tcL[r];
        float dt = pjt - tvL[r];
        int idx = (dt != dt) ? 0 : (int)fminf(fmaxf(dt, -200.f), 200.f) + 200;
        float fc = (float)cnt;
        aK = fmaf(fc, Ek_time[idx * H + c], aK);
        aV = fmaf(fc, Ev_time[idx * H + c], aV);
    }
    if (wave == 1 && nanT) {
        float fc = (float)nanT;
        aK = fmaf(fc, Ek_time[c], aK);
        aV = fmaf(fc, Ev_time[c], aV);
    }

    int lo = max(-25, j - (T - 1));
    int hi = min(25, j);
    for (int d = lo + wave; d <= hi; d += 4) {
        aK += Ek_pos[(d + 25) * H + c];
        aV += Ev_pos[(d + 25) * H + c];
    }
    if (wave == 0) {
        float c50 = (float)max(j - 25, 0);
        float c0 = (float)max((T - 26) - j, 0);
        aK = fmaf(c50, Ek_pos[50 * H + c], aK);
        aK = fmaf(c0, Ek_pos[0 * H + c], aK);
        aV = fmaf(c50, Ev_pos[50 * H + c], aV);
        aV = fmaf(c0, Ev_pos[0 * H + c], aV);
    }

    redK[tid] = aK;
    redV[tid] = aV;
    __syncthreads();

    if (tid < 64) {
        float sK = redK[tid] + redK[64 + tid] + redK[128 + tid] + redK[192 + tid];
        float sV = redV[tid] + redV[64 + tid] + redV[128 + tid] + redV[192 + tid];
        size_t o = (size_t)blockIdx.x * H + tid;
        k[o] = SCALE * k[o] + sK;
        v[o] = v[o] + sV;
    }
}

// ---------------------------------------------------------------------------
// Kernel 3: flash attention v3. Block = rows {g, 511-g}, grid B*256 (2
// blocks/CU). Waves 0,1 -> row g; waves 2,3 -> row 511-g; each wave takes
// every other 64-s tile with private online-softmax (m,l,acc); flash
// combine at the end. Staging/compute of neighbor blocks overlap.
// ---------------------------------------------------------------------------
__global__ __launch_bounds__(256) void attn_kernel(const float* __restrict__ q,
                                                   const float* __restrict__ kp,
                                                   const float* __restrict__ vp,
                                                   float* __restrict__ out) {
    int b = blockIdx.x >> 8;
    int g = blockIdx.x & 255;
    int tid = threadIdx.x;
    int wave = tid >> 6;
    int lane = tid & 63;

    int row = (wave < 2) ? g : (511 - g);
    int ns = row + 1;
    int nw = (ns + 63) >> 6;     // tiles this row needs
    int par = wave & 1;          // odd/even tile assignment

    __shared__ float kt[64 * 65];
    __shared__ float vt[64 * 64];
    __shared__ float qs[2][64];
    __shared__ float pS[4][64];
    __shared__ float mM[4], lM[4];
    __shared__ float accM[4][64];

    if (wave == 0) qs[0][lane] = q[((size_t)b * T + g) * H + lane];
    if (wave == 2) qs[1][lane] = q[((size_t)b * T + 511 - g) * H + lane];

    const float* kb = kp + (size_t)b * T * H;
    const float* vb = vp + (size_t)b * T * H;
    int ntiles = (512 - g + 63) >> 6;   // tiles for the long row (511-g)

    float m = -INFINITY;
    float l = 0.f;
    float acc = 0.f;
    const float* qw = qs[wave >> 1];

    for (int it = 0; it < ntiles; ++it) {
        int s0 = it * 64;

        // ---- cooperative stage (256 threads) ----
#pragma unroll
        for (int i = 0; i < 4; ++i) {
            int f = i * 256 + tid;
            int r = f >> 4;
            int c0 = (f & 15) << 2;
            int sr = min(s0 + r, T - 1);
            const float4 kv = *(const float4*)(kb + (size_t)sr * H + c0);
            const float4 vv = *(const float4*)(vb + (size_t)sr * H + c0);
            kt[r * 65 + c0 + 0] = kv.x;
            kt[r * 65 + c0 + 1] = kv.y;
            kt[r * 65 + c0 + 2] = kv.z;
            kt[r * 65 + c0 + 3] = kv.w;
            *(float4*)(vt + r * 64 + c0) = vv;
        }
        __syncthreads();

        if (it < nw && (it & 1) == par) {
            int s = s0 + lane;
            float sc = -INFINITY;
            if (s < ns) {
                const float* kr = kt + lane * 65;
                float d0 = 0.f, d1 = 0.f, d2 = 0.f, d3 = 0.f;
#pragma unroll
                for (int c = 0; c < 64; c += 4) {
                    d0 = fmaf(qw[c + 0], kr[c + 0], d0);
                    d1 = fmaf(qw[c + 1], kr[c + 1], d1);
                    d2 = fmaf(qw[c + 2], kr[c + 2], d2);
                    d3 = fmaf(qw[c + 3], kr[c + 3], d3);
                }
                sc = (d0 + d1) + (d2 + d3);
            }
            float mt = sc;
#pragma unroll
            for (int off = 32; off; off >>= 1) mt = fmaxf(mt, __shfl_xor(mt, off));
            float mnew = fmaxf(m, mt);
            float alpha = __expf(m - mnew);
            float p = (s < ns) ? __expf(sc - mnew) : 0.f;
            l = l * alpha + p;
            pS[wave][lane] = p;
            m = mnew;

            float a0 = 0.f, a1 = 0.f, a2 = 0.f, a3 = 0.f;
            int smax = min(64, ns - s0);
            const float* pw = pS[wave];
            int ss = 0;
            for (; ss + 4 <= smax; ss += 4) {
                a0 = fmaf(pw[ss + 0], vt[(ss + 0) * 64 + lane], a0);
                a1 = fmaf(pw[ss + 1], vt[(ss + 1) * 64 + lane], a1);
                a2 = fmaf(pw[ss + 2], vt[(ss + 2) * 64 + lane], a2);
                a3 = fmaf(pw[ss + 3], vt[(ss + 3) * 64 + lane], a3);
            }
            for (; ss < smax; ++ss)
                a0 = fmaf(pw[ss], vt[ss * 64 + lane], a0);
            acc = acc * alpha + ((a0 + a1) + (a2 + a3));
        }
        __syncthreads();
    }

    // ---- flash combine: merge the two waves of each row ----
    float lt = l;
#pragma unroll
    for (int off = 32; off; off >>= 1) lt += __shfl_xor(lt, off);
    mM[wave] = m;          // wave-uniform
    lM[wave] = lt;         // wave-uniform after xor-reduce
    accM[wave][lane] = acc;
    __syncthreads();

    if ((wave & 1) == 0) {
        int w1 = wave | 1;
        float m0 = mM[wave], m1 = mM[w1];
        float m12 = fmaxf(m0, m1);
        float al0 = __expf(m0 - m12);
        float al1 = __expf(m1 - m12);
        float lsum = lM[wave] * al0 + lM[w1] * al1;
        float o = (accM[wave][lane] * al0 + accM[w1][lane] * al1) / lsum;
        out[((size_t)b * T + row) * H + lane] = o;
    }
}

// ---------------------------------------------------------------------------
extern "C" void kernel_launch(void* const* d_in, const int* in_sizes, int n_in,
                              void* d_out, int out_size, void* d_ws, size_t ws_size,
                              hipStream_t stream) {
    const float* x        = (const float*)d_in[0];
    const int*   tok      = (const int*)d_in[1];
    const float* Wk       = (const float*)d_in[2];
    const float* Wq       = (const float*)d_in[3];
    const float* Wv       = (const float*)d_in[4];
    const float* Ek_pos   = (const float*)d_in[5];
    const float* Ev_pos   = (const float*)d_in[6];
    const float* Ek_time  = (const float*)d_in[7];
    const float* Ev_time  = (const float*)d_in[8];
    const float* Ek_pitch = (const float*)d_in[9];
    const float* Ev_pitch = (const float*)d_in[10];
    float* out = (float*)d_out;

    float* ws = (float*)d_ws;
    float* q      = ws;                        // B*T*H
    float* k      = q + B * T * H;             // B*T*H (becomes k')
    float* v      = k + B * T * H;             // B*T*H (becomes v')
    float* prop_t = v + B * T * H;             // B*T
    float* prop_p = prop_t + B * T;            // B*T
    int*   cntP   = (int*)(prop_p + B * T);    // B*129
    int*   meta   = cntP + B * 129;            // B*4
    float* tval   = (float*)(meta + B * 4);    // B*520
    int*   tcnt   = (int*)(tval + B * 520);    // B*520

    qkv_scan_kernel<<<192 + B, 256, 0, stream>>>(x, tok, Wq, Wk, Wv, q, k, v,
                                                 prop_t, prop_p, cntP, meta,
                                                 tval, tcnt);
    relsum_kernel<<<B * T, 256, 0, stream>>>(prop_t, prop_p, cntP, meta, tval, tcnt,
                                             Ek_pos, Ev_pos, Ek_time, Ev_time,
                                             Ek_pitch, Ev_pitch, k, v);
    attn_kernel<<<B * 256, 256, 0, stream>>>(q, k, v, out);
}

// Round 10
// 119.619 us; speedup vs baseline: 1.2657x; 1.0429x over previous
//
#include <hip/hip_runtime.h>
#include <math.h>

#define B 2
#define T 512
#define C 512
#define H 64

// scale = C^-0.5 = 1/sqrt(512)
#define SCALE 0.044194173824159216f

static __device__ __forceinline__ float qnan() { return __builtin_nanf(""); }

// ---------------------------------------------------------------------------
// Kernel 1: qkv projection with K-split (blocks 0..383) + token scans
// (blocks 384..385). Block = (k-half h, matrix m, 16-row group rg); each
// wave does 4 rows over 256 k-values (64 float4 W loads) -> partial buffers.
// ---------------------------------------------------------------------------
__global__ __launch_bounds__(256) void qkv_scan_kernel(
    const float* __restrict__ x, const int* __restrict__ tok,
    const float* __restrict__ Wq, const float* __restrict__ Wk,
    const float* __restrict__ Wv,
    float* __restrict__ q1, float* __restrict__ k1, float* __restrict__ v1,
    float* __restrict__ q2, float* __restrict__ k2, float* __restrict__ v2,
    float* __restrict__ prop_t, float* __restrict__ prop_p,
    int* __restrict__ cntP, int* __restrict__ meta,
    float* __restrict__ tval, int* __restrict__ tcnt) {
    int bid = blockIdx.x;
    int tid = threadIdx.x;
    int wave = tid >> 6;
    int lane = tid & 63;

    __shared__ float xs[16 * 256];   // 16 rows x half-C (16 KB)
    __shared__ int   tks[T];
    __shared__ int   cnts[520];
    __shared__ int   hist[129];
    __shared__ int   nanPc;

    if (bid < 384) {
        int h = bid / 192;             // k-half
        int rem = bid - h * 192;
        int m = rem >> 6;              // 0=q,1=k,2=v
        int rg = rem & 63;             // 16-row group
        int g = lane >> 4;
        int c4 = lane & 15;

        const float* Wm = (m == 0) ? Wq : ((m == 1) ? Wk : Wv);
        float* Om = (h == 0) ? ((m == 0) ? q1 : ((m == 1) ? k1 : v1))
                             : ((m == 0) ? q2 : ((m == 1) ? k2 : v2));

        // stage cols [h*256, h*256+256) of rows rg*16..+15
        const float* xbase = x + (size_t)rg * 16 * C + h * 256;
        for (int i = tid; i < 16 * 64; i += 256) {
            int r = i >> 6;
            int c0 = (i & 63) << 2;
            *(float4*)(xs + r * 256 + c0) =
                *(const float4*)(xbase + (size_t)r * C + c0);
        }
        __syncthreads();

        const float4* W4 = (const float4*)Wm;
        const float* xr = xs + (wave * 4) * 256;

        float4 a0 = make_float4(0.f, 0.f, 0.f, 0.f);
        float4 a1 = a0, a2 = a0, a3 = a0;
#pragma unroll 4
        for (int u = 0; u < 64; ++u) {
            int kk = u * 4 + g;                       // local k in half
            float4 w4 = W4[(h * 256 + kk) * 16 + c4];
            float x0 = xr[kk];
            float x1 = xr[256 + kk];
            float x2 = xr[512 + kk];
            float x3 = xr[768 + kk];
            a0.x = fmaf(x0, w4.x, a0.x); a0.y = fmaf(x0, w4.y, a0.y);
            a0.z = fmaf(x0, w4.z, a0.z); a0.w = fmaf(x0, w4.w, a0.w);
            a1.x = fmaf(x1, w4.x, a1.x); a1.y = fmaf(x1, w4.y, a1.y);
            a1.z = fmaf(x1, w4.z, a1.z); a1.w = fmaf(x1, w4.w, a1.w);
            a2.x = fmaf(x2, w4.x, a2.x); a2.y = fmaf(x2, w4.y, a2.y);
            a2.z = fmaf(x2, w4.z, a2.z); a2.w = fmaf(x2, w4.w, a2.w);
            a3.x = fmaf(x3, w4.x, a3.x); a3.y = fmaf(x3, w4.y, a3.y);
            a3.z = fmaf(x3, w4.z, a3.z); a3.w = fmaf(x3, w4.w, a3.w);
        }
#pragma unroll
        for (int mask = 16; mask <= 32; mask <<= 1) {
            a0.x += __shfl_xor(a0.x, mask); a0.y += __shfl_xor(a0.y, mask);
            a0.z += __shfl_xor(a0.z, mask); a0.w += __shfl_xor(a0.w, mask);
            a1.x += __shfl_xor(a1.x, mask); a1.y += __shfl_xor(a1.y, mask);
            a1.z += __shfl_xor(a1.z, mask); a1.w += __shfl_xor(a1.w, mask);
            a2.x += __shfl_xor(a2.x, mask); a2.y += __shfl_xor(a2.y, mask);
            a2.z += __shfl_xor(a2.z, mask); a2.w += __shfl_xor(a2.w, mask);
            a3.x += __shfl_xor(a3.x, mask); a3.y += __shfl_xor(a3.y, mask);
            a3.z += __shfl_xor(a3.z, mask); a3.w += __shfl_xor(a3.w, mask);
        }
        if (g == 0) {
            size_t row0 = (size_t)(rg * 16 + wave * 4);
            ((float4*)(Om + (row0 + 0) * H))[c4] = a0;
            ((float4*)(Om + (row0 + 1) * H))[c4] = a1;
            ((float4*)(Om + (row0 + 2) * H))[c4] = a2;
            ((float4*)(Om + (row0 + 3) * H))[c4] = a3;
        }
        return;
    }

    // ================= scan: blocks 384..385, wave 0 only =================
    int b = bid - 384;
    {
        const int* tb = tok + b * T;
        tks[tid] = tb[tid];
        tks[tid + 256] = tb[tid + 256];
        for (int i = tid; i < 520; i += 256) cnts[i] = 0;
        if (tid < 129) hist[tid] = 0;
        if (tid == 255) nanPc = 0;
    }
    __syncthreads();
    if (wave != 0) return;

    const int p0 = lane * 8;
    unsigned long long lowmask = lane ? ((1ull << lane) - 1ull) : 0ull;

    // ---- time scan ----
    float tv[8];
    {
        float lsum[8];
        bool lflag[8];
        float s = 0.f;
        bool f = false;
#pragma unroll
        for (int u = 0; u < 8; ++u) {
            int tk = tks[p0 + u];
            if (tk >= 288) { s += (float)(tk - 288); f = true; }
            lsum[u] = s;
            lflag[u] = f;
        }
        float inc = s;
#pragma unroll
        for (int off = 1; off < 64; off <<= 1) {
            float o = __shfl_up(inc, off);
            if (lane >= off) inc += o;
        }
        float ex = inc - s;
        unsigned long long fmask = __ballot(f);
        bool exf = (fmask & lowmask) != 0ull;
#pragma unroll
        for (int u = 0; u < 8; ++u) {
            bool have = exf | lflag[u];
            tv[u] = have ? rintf((ex + lsum[u] + 1.0f) / 10.0f) : qnan();
            prop_t[b * T + p0 + u] = tv[u];
        }
    }

    // ---- pitch scan (copy-last-valid) ----
    float fv[8];
    {
        bool lvalid[8];
        float cv = 0.f;
        bool cvd = false;
#pragma unroll
        for (int u = 0; u < 8; ++u) {
            int tk = tks[p0 + u];
            if (tk < 256) {
                cv = (float)((tk >= 128 ? tk - 128 : tk) + 1);
                cvd = true;
            }
            fv[u] = cv;
            lvalid[u] = cvd;
        }
        unsigned long long vmask = __ballot(cvd);
        unsigned long long lower = vmask & lowmask;
        bool exvd = lower != 0ull;
        int src = 63 - __clzll(lower | 1ull);
        float exv = __shfl(cv, src);
#pragma unroll
        for (int u = 0; u < 8; ++u) {
            bool hv = exvd | lvalid[u];
            fv[u] = lvalid[u] ? fv[u] : exv;
            fv[u] = hv ? fv[u] : qnan();
        }
    }

    // ---- shifted pitch + histogram ----
    {
        float nf0 = __shfl_down(fv[0], 1);
#pragma unroll
        for (int u = 0; u < 8; ++u) {
            float sv = (u < 7) ? fv[u + 1] : ((lane == 63) ? fv[7] : nf0);
            prop_p[b * T + p0 + u] = sv;
            if (sv == sv) atomicAdd(&hist[(int)sv - 1], 1);
            else atomicAdd(&nanPc, 1);
        }
    }

    // ---- time RLE ----
    {
        float pl7 = __shfl_up(tv[7], 1);
        int lstart[8];
        int lcnt = 0, lnan = 0;
#pragma unroll
        for (int u = 0; u < 8; ++u) {
            float cur = tv[u];
            bool val = (cur == cur);
            float pv = (u > 0) ? tv[u - 1] : pl7;
            bool st = false;
            if (val) {
                if (p0 + u == 0) st = true;
                else st = !(pv == pv) || (pv != cur);
            } else lnan++;
            lstart[u] = st;
            lcnt += st;
        }
        int incs = lcnt;
#pragma unroll
        for (int off = 1; off < 64; off <<= 1) {
            int o = __shfl_up(incs, off);
            if (lane >= off) incs += o;
        }
        int base = incs - lcnt;
        int Lruns = __shfl(incs, 63);
        int tn = lnan;
#pragma unroll
        for (int off = 32; off; off >>= 1) tn += __shfl_down(tn, off);
        tn = __shfl(tn, 0);

        int s2 = base;
#pragma unroll
        for (int u = 0; u < 8; ++u) {
            float cur = tv[u];
            if (lstart[u]) { tval[b * 520 + s2] = cur; s2++; }
            if (cur == cur) atomicAdd(&cnts[s2 - 1], 1);
        }
        for (int i = lane; i < Lruns; i += 64) tcnt[b * 520 + i] = cnts[i];
        for (int i = lane; i < 129; i += 64) cntP[b * 129 + i] = hist[i];
        if (lane == 0) {
            meta[b * 4] = Lruns;
            meta[b * 4 + 1] = tn;
        }
        if (lane == 1) meta[b * 4 + 2] = nanPc;
    }
}

// ---------------------------------------------------------------------------
// Kernel 2: relsum v3 — K/V split across blocks (grid 2048 = b x j x side),
// branchless unconditional gathers (clamped indices), fixed-trip loops.
// side 0: kf = SCALE*(k1+k2) + Rk ; side 1: vf = (v1+v2) + Rv.
// ---------------------------------------------------------------------------
__global__ __launch_bounds__(256) void relsum_kernel(
    const float* __restrict__ prop_t, const float* __restrict__ prop_p,
    const int* __restrict__ cntP, const int* __restrict__ meta,
    const float* __restrict__ tval, const int* __restrict__ tcnt,
    const float* __restrict__ Ek_pos, const float* __restrict__ Ev_pos,
    const float* __restrict__ Ek_time, const float* __restrict__ Ev_time,
    const float* __restrict__ Ek_pitch, const float* __restrict__ Ev_pitch,
    const float* __restrict__ k1, const float* __restrict__ k2,
    const float* __restrict__ v1, const float* __restrict__ v2,
    float* __restrict__ kf, float* __restrict__ vf) {
    int bid = blockIdx.x;
    int side = bid & 1;
    int j = (bid >> 1) & 511;
    int b = bid >> 10;
    int tid = threadIdx.x;
    int wave = tid >> 6;
    int c = tid & 63;

    const float* Ep = side ? Ev_pitch : Ek_pitch;
    const float* Et = side ? Ev_time : Ek_time;
    const float* Eo = side ? Ev_pos : Ek_pos;

    __shared__ float tvL[520];
    __shared__ int tcL[520];
    __shared__ int cpL[132];
    __shared__ float red[256];

    int L = meta[b * 4];
    int nanT = meta[b * 4 + 1];
    int nanP = meta[b * 4 + 2];
    for (int i = tid; i < L; i += 256) {
        tvL[i] = tval[b * 520 + i];
        tcL[i] = tcnt[b * 520 + i];
    }
    if (tid < 129) cpL[tid] = cntP[b * 129 + tid];
    else if (tid < 132) cpL[tid] = 0;
    __syncthreads();

    float pjt = prop_t[b * T + j];
    float pjp = prop_p[b * T + j];
    bool pvalid = (pjp == pjp);
    int ipjp = pvalid ? (int)pjp : 0;

    float a = 0.f;

    // ---- pitch: 33 fixed trips, unconditional clamped gathers ----
#pragma unroll 4
    for (int i = 0; i < 33; ++i) {
        int e = wave + i * 4;                 // 0..131 (cpL zero-padded)
        float fc = (float)cpL[e];
        int idx = pvalid ? (ipjp + 127 - e) : 0;
        idx = min(max(idx, 0), 255);
        a = fmaf(fc, Ep[idx * H + c], a);
    }
    if (wave == 3) a = fmaf((float)nanP, Ep[c], a);

    // ---- time runs (ternary select, no if-guard) ----
#pragma unroll 2
    for (int r = wave; r < L; r += 4) {
        float fc = (float)tcL[r];
        float dt = pjt - tvL[r];
        int idx = (dt != dt) ? 0 : (int)fminf(fmaxf(dt, -200.f), 200.f) + 200;
        a = fmaf(fc, Et[idx * H + c], a);
    }
    if (wave == 1) a = fmaf((float)nanT, Et[c], a);

    // ---- pos: fixed 13 trips with 0/1 weight + edge multiplicities ----
    int lo = max(-25, j - (T - 1));
    int hi = min(25, j);
#pragma unroll
    for (int i = 0; i < 13; ++i) {
        int d = -25 + wave + i * 4;           // -25..26
        float w = (d >= lo && d <= hi) ? 1.f : 0.f;
        int idx = min(d + 25, 50);
        a = fmaf(w, Eo[idx * H + c], a);
    }
    if (wave == 0) {
        a = fmaf((float)max(j - 25, 0), Eo[50 * H + c], a);
        a = fmaf((float)max((T - 26) - j, 0), Eo[c], a);
    }

    red[tid] = a;
    __syncthreads();

    if (tid < 64) {
        float s = red[tid] + red[64 + tid] + red[128 + tid] + red[192 + tid];
        size_t o = (size_t)(b * T + j) * H + tid;
        if (side == 0) kf[o] = SCALE * (k1[o] + k2[o]) + s;
        else           vf[o] = (v1[o] + v2[o]) + s;
    }
}

// ---------------------------------------------------------------------------
// Kernel 3: flash attention (R9 structure). Block = rows {g, 511-g}; waves
// 0,1 -> row g (even/odd tiles), waves 2,3 -> row 511-g; private online
// softmax per wave, flash combine at the end. q read as q1+q2.
// ---------------------------------------------------------------------------
__global__ __launch_bounds__(256) void attn_kernel(const float* __restrict__ q1,
                                                   const float* __restrict__ q2,
                                                   const float* __restrict__ kp,
                                                   const float* __restrict__ vp,
                                                   float* __restrict__ out) {
    int b = blockIdx.x >> 8;
    int g = blockIdx.x & 255;
    int tid = threadIdx.x;
    int wave = tid >> 6;
    int lane = tid & 63;

    int row = (wave < 2) ? g : (511 - g);
    int ns = row + 1;
    int nw = (ns + 63) >> 6;
    int par = wave & 1;

    __shared__ float kt[64 * 65];
    __shared__ float vt[64 * 64];
    __shared__ float qs[2][64];
    __shared__ float pS[4][64];
    __shared__ float mM[4], lM[4];
    __shared__ float accM[4][64];

    if (wave == 0) {
        size_t o = ((size_t)b * T + g) * H + lane;
        qs[0][lane] = q1[o] + q2[o];
    }
    if (wave == 2) {
        size_t o = ((size_t)b * T + 511 - g) * H + lane;
        qs[1][lane] = q1[o] + q2[o];
    }

    const float* kb = kp + (size_t)b * T * H;
    const float* vb = vp + (size_t)b * T * H;
    int ntiles = (512 - g + 63) >> 6;

    float m = -INFINITY;
    float l = 0.f;
    float acc = 0.f;
    const float* qw = qs[wave >> 1];

    for (int it = 0; it < ntiles; ++it) {
        int s0 = it * 64;

#pragma unroll
        for (int i = 0; i < 4; ++i) {
            int f = i * 256 + tid;
            int r = f >> 4;
            int c0 = (f & 15) << 2;
            int sr = min(s0 + r, T - 1);
            const float4 kv = *(const float4*)(kb + (size_t)sr * H + c0);
            const float4 vv = *(const float4*)(vb + (size_t)sr * H + c0);
            kt[r * 65 + c0 + 0] = kv.x;
            kt[r * 65 + c0 + 1] = kv.y;
            kt[r * 65 + c0 + 2] = kv.z;
            kt[r * 65 + c0 + 3] = kv.w;
            *(float4*)(vt + r * 64 + c0) = vv;
        }
        __syncthreads();

        if (it < nw && (it & 1) == par) {
            int s = s0 + lane;
            float sc = -INFINITY;
            if (s < ns) {
                const float* kr = kt + lane * 65;
                float d0 = 0.f, d1 = 0.f, d2 = 0.f, d3 = 0.f;
#pragma unroll
                for (int c = 0; c < 64; c += 4) {
                    d0 = fmaf(qw[c + 0], kr[c + 0], d0);
                    d1 = fmaf(qw[c + 1], kr[c + 1], d1);
                    d2 = fmaf(qw[c + 2], kr[c + 2], d2);
                    d3 = fmaf(qw[c + 3], kr[c + 3], d3);
                }
                sc = (d0 + d1) + (d2 + d3);
            }
            float mt = sc;
#pragma unroll
            for (int off = 32; off; off >>= 1) mt = fmaxf(mt, __shfl_xor(mt, off));
            float mnew = fmaxf(m, mt);
            float alpha = __expf(m - mnew);
            float p = (s < ns) ? __expf(sc - mnew) : 0.f;
            l = l * alpha + p;
            pS[wave][lane] = p;
            m = mnew;

            float a0 = 0.f, a1 = 0.f, a2 = 0.f, a3 = 0.f;
            int smax = min(64, ns - s0);
            const float* pw = pS[wave];
            int ss = 0;
            for (; ss + 4 <= smax; ss += 4) {
                a0 = fmaf(pw[ss + 0], vt[(ss + 0) * 64 + lane], a0);
                a1 = fmaf(pw[ss + 1], vt[(ss + 1) * 64 + lane], a1);
                a2 = fmaf(pw[ss + 2], vt[(ss + 2) * 64 + lane], a2);
                a3 = fmaf(pw[ss + 3], vt[(ss + 3) * 64 + lane], a3);
            }
            for (; ss < smax; ++ss)
                a0 = fmaf(pw[ss], vt[ss * 64 + lane], a0);
            acc = acc * alpha + ((a0 + a1) + (a2 + a3));
        }
        __syncthreads();
    }

    float lt = l;
#pragma unroll
    for (int off = 32; off; off >>= 1) lt += __shfl_xor(lt, off);
    mM[wave] = m;
    lM[wave] = lt;
    accM[wave][lane] = acc;
    __syncthreads();

    if ((wave & 1) == 0) {
        int w1 = wave | 1;
        float m0 = mM[wave], m1 = mM[w1];
        float m12 = fmaxf(m0, m1);
        float al0 = __expf(m0 - m12);
        float al1 = __expf(m1 - m12);
        float lsum = lM[wave] * al0 + lM[w1] * al1;
        float o = (accM[wave][lane] * al0 + accM[w1][lane] * al1) / lsum;
        out[((size_t)b * T + row) * H + lane] = o;
    }
}

// ---------------------------------------------------------------------------
extern "C" void kernel_launch(void* const* d_in, const int* in_sizes, int n_in,
                              void* d_out, int out_size, void* d_ws, size_t ws_size,
                              hipStream_t stream) {
    const float* x        = (const float*)d_in[0];
    const int*   tok      = (const int*)d_in[1];
    const float* Wk       = (const float*)d_in[2];
    const float* Wq       = (const float*)d_in[3];
    const float* Wv       = (const float*)d_in[4];
    const float* Ek_pos   = (const float*)d_in[5];
    const float* Ev_pos   = (const float*)d_in[6];
    const float* Ek_time  = (const float*)d_in[7];
    const float* Ev_time  = (const float*)d_in[8];
    const float* Ek_pitch = (const float*)d_in[9];
    const float* Ev_pitch = (const float*)d_in[10];
    float* out = (float*)d_out;

    const int N = B * T * H;
    float* ws = (float*)d_ws;
    float* q1 = ws;            // partials
    float* k1 = q1 + N;
    float* v1 = k1 + N;
    float* q2 = v1 + N;
    float* k2 = q2 + N;
    float* v2 = k2 + N;
    float* kf = v2 + N;        // finals
    float* vf = kf + N;
    float* prop_t = vf + N;                    // B*T
    float* prop_p = prop_t + B * T;            // B*T
    int*   cntP   = (int*)(prop_p + B * T);    // B*129
    int*   meta   = cntP + B * 129;            // B*4
    float* tval   = (float*)(meta + B * 4);    // B*520
    int*   tcnt   = (int*)(tval + B * 520);    // B*520

    qkv_scan_kernel<<<384 + B, 256, 0, stream>>>(x, tok, Wq, Wk, Wv,
                                                 q1, k1, v1, q2, k2, v2,
                                                 prop_t, prop_p, cntP, meta,
                                                 tval, tcnt);
    relsum_kernel<<<B * T * 2, 256, 0, stream>>>(prop_t, prop_p, cntP, meta,
                                                 tval, tcnt,
                                                 Ek_pos, Ev_pos, Ek_time, Ev_time,
                                                 Ek_pitch, Ev_pitch,
                                                 k1, k2, v1, v2, kf, vf);
    attn_kernel<<<B * 256, 256, 0, stream>>>(q1, q2, kf, vf, out);
}

// Round 11
// 114.100 us; speedup vs baseline: 1.3269x; 1.0484x over previous
//
#include <hip/hip_runtime.h>
#include <math.h>

#define B 2
#define T 512
#define C 512
#define H 64

// scale = C^-0.5 = 1/sqrt(512)
#define SCALE 0.044194173824159216f

static __device__ __forceinline__ float qnan() { return __builtin_nanf(""); }

// ---------------------------------------------------------------------------
// Kernel 1: qkv projection with K-split (blocks 0..383) + token scans
// (blocks 384..385). Unchanged from R10.
// ---------------------------------------------------------------------------
__global__ __launch_bounds__(256) void qkv_scan_kernel(
    const float* __restrict__ x, const int* __restrict__ tok,
    const float* __restrict__ Wq, const float* __restrict__ Wk,
    const float* __restrict__ Wv,
    float* __restrict__ q1, float* __restrict__ k1, float* __restrict__ v1,
    float* __restrict__ q2, float* __restrict__ k2, float* __restrict__ v2,
    float* __restrict__ prop_t, float* __restrict__ prop_p,
    int* __restrict__ cntP, int* __restrict__ meta,
    float* __restrict__ tval, int* __restrict__ tcnt) {
    int bid = blockIdx.x;
    int tid = threadIdx.x;
    int wave = tid >> 6;
    int lane = tid & 63;

    __shared__ float xs[16 * 256];
    __shared__ int   tks[T];
    __shared__ int   cnts[520];
    __shared__ int   hist[129];
    __shared__ int   nanPc;

    if (bid < 384) {
        int h = bid / 192;
        int rem = bid - h * 192;
        int m = rem >> 6;
        int rg = rem & 63;
        int g = lane >> 4;
        int c4 = lane & 15;

        const float* Wm = (m == 0) ? Wq : ((m == 1) ? Wk : Wv);
        float* Om = (h == 0) ? ((m == 0) ? q1 : ((m == 1) ? k1 : v1))
                             : ((m == 0) ? q2 : ((m == 1) ? k2 : v2));

        const float* xbase = x + (size_t)rg * 16 * C + h * 256;
        for (int i = tid; i < 16 * 64; i += 256) {
            int r = i >> 6;
            int c0 = (i & 63) << 2;
            *(float4*)(xs + r * 256 + c0) =
                *(const float4*)(xbase + (size_t)r * C + c0);
        }
        __syncthreads();

        const float4* W4 = (const float4*)Wm;
        const float* xr = xs + (wave * 4) * 256;

        float4 a0 = make_float4(0.f, 0.f, 0.f, 0.f);
        float4 a1 = a0, a2 = a0, a3 = a0;
#pragma unroll 4
        for (int u = 0; u < 64; ++u) {
            int kk = u * 4 + g;
            float4 w4 = W4[(h * 256 + kk) * 16 + c4];
            float x0 = xr[kk];
            float x1 = xr[256 + kk];
            float x2 = xr[512 + kk];
            float x3 = xr[768 + kk];
            a0.x = fmaf(x0, w4.x, a0.x); a0.y = fmaf(x0, w4.y, a0.y);
            a0.z = fmaf(x0, w4.z, a0.z); a0.w = fmaf(x0, w4.w, a0.w);
            a1.x = fmaf(x1, w4.x, a1.x); a1.y = fmaf(x1, w4.y, a1.y);
            a1.z = fmaf(x1, w4.z, a1.z); a1.w = fmaf(x1, w4.w, a1.w);
            a2.x = fmaf(x2, w4.x, a2.x); a2.y = fmaf(x2, w4.y, a2.y);
            a2.z = fmaf(x2, w4.z, a2.z); a2.w = fmaf(x2, w4.w, a2.w);
            a3.x = fmaf(x3, w4.x, a3.x); a3.y = fmaf(x3, w4.y, a3.y);
            a3.z = fmaf(x3, w4.z, a3.z); a3.w = fmaf(x3, w4.w, a3.w);
        }
#pragma unroll
        for (int mask = 16; mask <= 32; mask <<= 1) {
            a0.x += __shfl_xor(a0.x, mask); a0.y += __shfl_xor(a0.y, mask);
            a0.z += __shfl_xor(a0.z, mask); a0.w += __shfl_xor(a0.w, mask);
            a1.x += __shfl_xor(a1.x, mask); a1.y += __shfl_xor(a1.y, mask);
            a1.z += __shfl_xor(a1.z, mask); a1.w += __shfl_xor(a1.w, mask);
            a2.x += __shfl_xor(a2.x, mask); a2.y += __shfl_xor(a2.y, mask);
            a2.z += __shfl_xor(a2.z, mask); a2.w += __shfl_xor(a2.w, mask);
            a3.x += __shfl_xor(a3.x, mask); a3.y += __shfl_xor(a3.y, mask);
            a3.z += __shfl_xor(a3.z, mask); a3.w += __shfl_xor(a3.w, mask);
        }
        if (g == 0) {
            size_t row0 = (size_t)(rg * 16 + wave * 4);
            ((float4*)(Om + (row0 + 0) * H))[c4] = a0;
            ((float4*)(Om + (row0 + 1) * H))[c4] = a1;
            ((float4*)(Om + (row0 + 2) * H))[c4] = a2;
            ((float4*)(Om + (row0 + 3) * H))[c4] = a3;
        }
        return;
    }

    // ================= scan: blocks 384..385, wave 0 only =================
    int b = bid - 384;
    {
        const int* tb = tok + b * T;
        tks[tid] = tb[tid];
        tks[tid + 256] = tb[tid + 256];
        for (int i = tid; i < 520; i += 256) cnts[i] = 0;
        if (tid < 129) hist[tid] = 0;
        if (tid == 255) nanPc = 0;
    }
    __syncthreads();
    if (wave != 0) return;

    const int p0 = lane * 8;
    unsigned long long lowmask = lane ? ((1ull << lane) - 1ull) : 0ull;

    // ---- time scan ----
    float tv[8];
    {
        float lsum[8];
        bool lflag[8];
        float s = 0.f;
        bool f = false;
#pragma unroll
        for (int u = 0; u < 8; ++u) {
            int tk = tks[p0 + u];
            if (tk >= 288) { s += (float)(tk - 288); f = true; }
            lsum[u] = s;
            lflag[u] = f;
        }
        float inc = s;
#pragma unroll
        for (int off = 1; off < 64; off <<= 1) {
            float o = __shfl_up(inc, off);
            if (lane >= off) inc += o;
        }
        float ex = inc - s;
        unsigned long long fmask = __ballot(f);
        bool exf = (fmask & lowmask) != 0ull;
#pragma unroll
        for (int u = 0; u < 8; ++u) {
            bool have = exf | lflag[u];
            tv[u] = have ? rintf((ex + lsum[u] + 1.0f) / 10.0f) : qnan();
            prop_t[b * T + p0 + u] = tv[u];
        }
    }

    // ---- pitch scan (copy-last-valid) ----
    float fv[8];
    {
        bool lvalid[8];
        float cv = 0.f;
        bool cvd = false;
#pragma unroll
        for (int u = 0; u < 8; ++u) {
            int tk = tks[p0 + u];
            if (tk < 256) {
                cv = (float)((tk >= 128 ? tk - 128 : tk) + 1);
                cvd = true;
            }
            fv[u] = cv;
            lvalid[u] = cvd;
        }
        unsigned long long vmask = __ballot(cvd);
        unsigned long long lower = vmask & lowmask;
        bool exvd = lower != 0ull;
        int src = 63 - __clzll(lower | 1ull);
        float exv = __shfl(cv, src);
#pragma unroll
        for (int u = 0; u < 8; ++u) {
            bool hv = exvd | lvalid[u];
            fv[u] = lvalid[u] ? fv[u] : exv;
            fv[u] = hv ? fv[u] : qnan();
        }
    }

    // ---- shifted pitch + histogram ----
    {
        float nf0 = __shfl_down(fv[0], 1);
#pragma unroll
        for (int u = 0; u < 8; ++u) {
            float sv = (u < 7) ? fv[u + 1] : ((lane == 63) ? fv[7] : nf0);
            prop_p[b * T + p0 + u] = sv;
            if (sv == sv) atomicAdd(&hist[(int)sv - 1], 1);
            else atomicAdd(&nanPc, 1);
        }
    }

    // ---- time RLE ----
    {
        float pl7 = __shfl_up(tv[7], 1);
        int lstart[8];
        int lcnt = 0, lnan = 0;
#pragma unroll
        for (int u = 0; u < 8; ++u) {
            float cur = tv[u];
            bool val = (cur == cur);
            float pv = (u > 0) ? tv[u - 1] : pl7;
            bool st = false;
            if (val) {
                if (p0 + u == 0) st = true;
                else st = !(pv == pv) || (pv != cur);
            } else lnan++;
            lstart[u] = st;
            lcnt += st;
        }
        int incs = lcnt;
#pragma unroll
        for (int off = 1; off < 64; off <<= 1) {
            int o = __shfl_up(incs, off);
            if (lane >= off) incs += o;
        }
        int base = incs - lcnt;
        int Lruns = __shfl(incs, 63);
        int tn = lnan;
#pragma unroll
        for (int off = 32; off; off >>= 1) tn += __shfl_down(tn, off);
        tn = __shfl(tn, 0);

        int s2 = base;
#pragma unroll
        for (int u = 0; u < 8; ++u) {
            float cur = tv[u];
            if (lstart[u]) { tval[b * 520 + s2] = cur; s2++; }
            if (cur == cur) atomicAdd(&cnts[s2 - 1], 1);
        }
        for (int i = lane; i < Lruns; i += 64) tcnt[b * 520 + i] = cnts[i];
        for (int i = lane; i < 129; i += 64) cntP[b * 129 + i] = hist[i];
        if (lane == 0) {
            meta[b * 4] = Lruns;
            meta[b * 4 + 1] = tn;
        }
        if (lane == 1) meta[b * 4 + 2] = nanPc;
    }
}

// ---------------------------------------------------------------------------
// Kernel 2: relsum v3 (unchanged from R10).
// ---------------------------------------------------------------------------
__global__ __launch_bounds__(256) void relsum_kernel(
    const float* __restrict__ prop_t, const float* __restrict__ prop_p,
    const int* __restrict__ cntP, const int* __restrict__ meta,
    const float* __restrict__ tval, const int* __restrict__ tcnt,
    const float* __restrict__ Ek_pos, const float* __restrict__ Ev_pos,
    const float* __restrict__ Ek_time, const float* __restrict__ Ev_time,
    const float* __restrict__ Ek_pitch, const float* __restrict__ Ev_pitch,
    const float* __restrict__ k1, const float* __restrict__ k2,
    const float* __restrict__ v1, const float* __restrict__ v2,
    float* __restrict__ kf, float* __restrict__ vf) {
    int bid = blockIdx.x;
    int side = bid & 1;
    int j = (bid >> 1) & 511;
    int b = bid >> 10;
    int tid = threadIdx.x;
    int wave = tid >> 6;
    int c = tid & 63;

    const float* Ep = side ? Ev_pitch : Ek_pitch;
    const float* Et = side ? Ev_time : Ek_time;
    const float* Eo = side ? Ev_pos : Ek_pos;

    __shared__ float tvL[520];
    __shared__ int tcL[520];
    __shared__ int cpL[132];
    __shared__ float red[256];

    int L = meta[b * 4];
    int nanT = meta[b * 4 + 1];
    int nanP = meta[b * 4 + 2];
    for (int i = tid; i < L; i += 256) {
        tvL[i] = tval[b * 520 + i];
        tcL[i] = tcnt[b * 520 + i];
    }
    if (tid < 129) cpL[tid] = cntP[b * 129 + tid];
    else if (tid < 132) cpL[tid] = 0;
    __syncthreads();

    float pjt = prop_t[b * T + j];
    float pjp = prop_p[b * T + j];
    bool pvalid = (pjp == pjp);
    int ipjp = pvalid ? (int)pjp : 0;

    float a = 0.f;

#pragma unroll 4
    for (int i = 0; i < 33; ++i) {
        int e = wave + i * 4;
        float fc = (float)cpL[e];
        int idx = pvalid ? (ipjp + 127 - e) : 0;
        idx = min(max(idx, 0), 255);
        a = fmaf(fc, Ep[idx * H + c], a);
    }
    if (wave == 3) a = fmaf((float)nanP, Ep[c], a);

#pragma unroll 2
    for (int r = wave; r < L; r += 4) {
        float fc = (float)tcL[r];
        float dt = pjt - tvL[r];
        int idx = (dt != dt) ? 0 : (int)fminf(fmaxf(dt, -200.f), 200.f) + 200;
        a = fmaf(fc, Et[idx * H + c], a);
    }
    if (wave == 1) a = fmaf((float)nanT, Et[c], a);

    int lo = max(-25, j - (T - 1));
    int hi = min(25, j);
#pragma unroll
    for (int i = 0; i < 13; ++i) {
        int d = -25 + wave + i * 4;
        float w = (d >= lo && d <= hi) ? 1.f : 0.f;
        int idx = min(d + 25, 50);
        a = fmaf(w, Eo[idx * H + c], a);
    }
    if (wave == 0) {
        a = fmaf((float)max(j - 25, 0), Eo[50 * H + c], a);
        a = fmaf((float)max((T - 26) - j, 0), Eo[c], a);
    }

    red[tid] = a;
    __syncthreads();

    if (tid < 64) {
        float s = red[tid] + red[64 + tid] + red[128 + tid] + red[192 + tid];
        size_t o = (size_t)(b * T + j) * H + tid;
        if (side == 0) kf[o] = SCALE * (k1[o] + k2[o]) + s;
        else           vf[o] = (v1[o] + v2[o]) + s;
    }
}

// ---------------------------------------------------------------------------
// Kernel 3: flash attention v4 — 128-row k/v tiles (68 KB LDS, 2 blocks/CU).
// Block = rows {g, 511-g}; the two waves of a row take the two 64-sub-tiles
// within each 128-tile (both active every iteration). Barriers halved vs R10;
// staging bursts are 16 float4 loads/thread (deeper MLP). Flash combine at
// the end merges the wave pair.
// ---------------------------------------------------------------------------
__global__ __launch_bounds__(256) void attn_kernel(const float* __restrict__ q1,
                                                   const float* __restrict__ q2,
                                                   const float* __restrict__ kp,
                                                   const float* __restrict__ vp,
                                                   float* __restrict__ out) {
    int b = blockIdx.x >> 8;
    int g = blockIdx.x & 255;
    int tid = threadIdx.x;
    int wave = tid >> 6;
    int lane = tid & 63;

    int row = (wave < 2) ? g : (511 - g);
    int ns = row + 1;
    int par = wave & 1;          // which 64-sub-tile of the 128-tile

    __shared__ float kt[128 * 65];   // 33.3 KB
    __shared__ float vt[128 * 64];   // 32.8 KB
    __shared__ float qs[2][64];
    __shared__ float pS[4][64];
    __shared__ float mM[4], lM[4];
    __shared__ float accM[4][64];

    if (wave == 0) {
        size_t o = ((size_t)b * T + g) * H + lane;
        qs[0][lane] = q1[o] + q2[o];
    }
    if (wave == 2) {
        size_t o = ((size_t)b * T + 511 - g) * H + lane;
        qs[1][lane] = q1[o] + q2[o];
    }

    const float* kb = kp + (size_t)b * T * H;
    const float* vb = vp + (size_t)b * T * H;
    int ntiles = (512 - g + 127) >> 7;   // 128-tiles covering the long row

    float m = -INFINITY;
    float l = 0.f;
    float acc = 0.f;
    const float* qw = qs[wave >> 1];

    for (int it = 0; it < ntiles; ++it) {
        int s0 = it * 128;

        // ---- cooperative stage: 128 rows of k and v (16 float4/thread) ----
#pragma unroll
        for (int i = 0; i < 8; ++i) {
            int f = i * 256 + tid;          // float4 index 0..2047
            int r = f >> 4;                 // tile row 0..127
            int c0 = (f & 15) << 2;         // col 0..60
            int sr = min(s0 + r, T - 1);
            const float4 kv = *(const float4*)(kb + (size_t)sr * H + c0);
            const float4 vv = *(const float4*)(vb + (size_t)sr * H + c0);
            kt[r * 65 + c0 + 0] = kv.x;
            kt[r * 65 + c0 + 1] = kv.y;
            kt[r * 65 + c0 + 2] = kv.z;
            kt[r * 65 + c0 + 3] = kv.w;
            *(float4*)(vt + r * 64 + c0) = vv;
        }
        __syncthreads();

        int sw0 = s0 + par * 64;            // this wave's sub-tile start
        if (sw0 < ns) {
            int s = sw0 + lane;
            float sc = -INFINITY;
            if (s < ns) {
                const float* kr = kt + (par * 64 + lane) * 65;
                float d0 = 0.f, d1 = 0.f, d2 = 0.f, d3 = 0.f;
#pragma unroll
                for (int c = 0; c < 64; c += 4) {
                    d0 = fmaf(qw[c + 0], kr[c + 0], d0);
                    d1 = fmaf(qw[c + 1], kr[c + 1], d1);
                    d2 = fmaf(qw[c + 2], kr[c + 2], d2);
                    d3 = fmaf(qw[c + 3], kr[c + 3], d3);
                }
                sc = (d0 + d1) + (d2 + d3);
            }
            float mt = sc;
#pragma unroll
            for (int off = 32; off; off >>= 1) mt = fmaxf(mt, __shfl_xor(mt, off));
            float mnew = fmaxf(m, mt);
            float alpha = __expf(m - mnew);
            float p = (s < ns) ? __expf(sc - mnew) : 0.f;
            l = l * alpha + p;
            pS[wave][lane] = p;
            m = mnew;

            float a0 = 0.f, a1 = 0.f, a2 = 0.f, a3 = 0.f;
            int smax = min(64, ns - sw0);
            const float* pw = pS[wave];
            const float* vbse = vt + par * 64 * 64;
            int ss = 0;
            for (; ss + 4 <= smax; ss += 4) {
                a0 = fmaf(pw[ss + 0], vbse[(ss + 0) * 64 + lane], a0);
                a1 = fmaf(pw[ss + 1], vbse[(ss + 1) * 64 + lane], a1);
                a2 = fmaf(pw[ss + 2], vbse[(ss + 2) * 64 + lane], a2);
                a3 = fmaf(pw[ss + 3], vbse[(ss + 3) * 64 + lane], a3);
            }
            for (; ss < smax; ++ss)
                a0 = fmaf(pw[ss], vbse[ss * 64 + lane], a0);
            acc = acc * alpha + ((a0 + a1) + (a2 + a3));
        }
        __syncthreads();
    }

    // ---- flash combine: merge the two waves of each row ----
    float lt = l;
#pragma unroll
    for (int off = 32; off; off >>= 1) lt += __shfl_xor(lt, off);
    mM[wave] = m;
    lM[wave] = lt;
    accM[wave][lane] = acc;
    __syncthreads();

    if ((wave & 1) == 0) {
        int w1 = wave | 1;
        float m0 = mM[wave], m1 = mM[w1];
        float m12 = fmaxf(m0, m1);
        float al0 = __expf(m0 - m12);
        float al1 = __expf(m1 - m12);
        float lsum = lM[wave] * al0 + lM[w1] * al1;
        float o = (accM[wave][lane] * al0 + accM[w1][lane] * al1) / lsum;
        out[((size_t)b * T + row) * H + lane] = o;
    }
}

// ---------------------------------------------------------------------------
extern "C" void kernel_launch(void* const* d_in, const int* in_sizes, int n_in,
                              void* d_out, int out_size, void* d_ws, size_t ws_size,
                              hipStream_t stream) {
    const float* x        = (const float*)d_in[0];
    const int*   tok      = (const int*)d_in[1];
    const float* Wk       = (const float*)d_in[2];
    const float* Wq       = (const float*)d_in[3];
    const float* Wv       = (const float*)d_in[4];
    const float* Ek_pos   = (const float*)d_in[5];
    const float* Ev_pos   = (const float*)d_in[6];
    const float* Ek_time  = (const float*)d_in[7];
    const float* Ev_time  = (const float*)d_in[8];
    const float* Ek_pitch = (const float*)d_in[9];
    const float* Ev_pitch = (const float*)d_in[10];
    float* out = (float*)d_out;

    const int N = B * T * H;
    float* ws = (float*)d_ws;
    float* q1 = ws;
    float* k1 = q1 + N;
    float* v1 = k1 + N;
    float* q2 = v1 + N;
    float* k2 = q2 + N;
    float* v2 = k2 + N;
    float* kf = v2 + N;
    float* vf = kf + N;
    float* prop_t = vf + N;
    float* prop_p = prop_t + B * T;
    int*   cntP   = (int*)(prop_p + B * T);
    int*   meta   = cntP + B * 129;
    float* tval   = (float*)(meta + B * 4);
    int*   tcnt   = (int*)(tval + B * 520);

    qkv_scan_kernel<<<384 + B, 256, 0, stream>>>(x, tok, Wq, Wk, Wv,
                                                 q1, k1, v1, q2, k2, v2,
                                                 prop_t, prop_p, cntP, meta,
                                                 tval, tcnt);
    relsum_kernel<<<B * T * 2, 256, 0, stream>>>(prop_t, prop_p, cntP, meta,
                                                 tval, tcnt,
                                                 Ek_pos, Ev_pos, Ek_time, Ev_time,
                                                 Ek_pitch, Ev_pitch,
                                                 k1, k2, v1, v2, kf, vf);
    attn_kernel<<<B * 256, 256, 0, stream>>>(q1, q2, kf, vf, out);
}